// Round 5
// baseline (246.337 us; speedup 1.0000x reference)
//
#include <hip/hip_runtime.h>

// Laplace transform forward: out[n,i,f] = e[i]*out[n-1,i,f] + decay[i]*inp[n,f]
// T=2048, F=256, N_S=108. float32 in / float32 out.
//
// R7: (a) nontemporal stores on the LOAD-FREE burst, (b) constants hoisted
// to a 1-block init kernel (table in ws).
// R6 post-mortem: pure store burst (no vmcnt waits, 27 waves/CU) still
// ~2.7 TB/s vs fill's 6.5 with 3 waves/CU -> store-issue, occupancy, vmcnt
// all exonerated. Remaining theory: cached stores stream 226MB through 32MB
// L2; what reaches HBM is the EVICTION stream = address-scattered 128B
// granules from 6912 interleaved wave-streams (fill's sweeping contiguous
// window evicts clustered lines). NT stores bypass L2 and reach HBM in
// issue order (1KB/wave, 4KB/block-slice). R3's NT datapoint was confounded
// by global loads inside the loop (NT acks serialized behind load waits);
// NT + load-free burst is the clean test.
//
// init: 1 block computes e/decay/g tables (removes ~300 serial VALU cycles
//       of powf/expf per thread from A and C starts, ~10us total)
// Phase A: locals L_b for 64 chunks (1728 blocks, 7MB ws writes)
// Phase B: sequential combine (27 blocks) -> exact entering states in ws
// Phase C: load-free NT burst, grid (27, 64), 32KB LDS, 226.5MB stream.
// Kernel floor: 226.5MB / 6.3TB/s ~= 36us.

#define T_LEN 2048
#define F_DIM 256
#define NS    108      // NTAU + 2*K = 100 + 8
#define KPAD  4
#define CH    32            // chunk length (A/B/C all use 32)
#define NB    (T_LEN / CH)  // 64

#define STATE_FLOATS ((size_t)NB * NS * 64 * 4)   // 1,769,472 floats
// const table lives at ws + STATE_FLOATS: [e:108][d:108][g:108]

typedef float f32x4 __attribute__((ext_vector_type(4)));

__device__ __forceinline__ void laplace_consts(int i, float& s, float& e, float& decay) {
    const float c   = powf(20.0f, 1.0f / 99.0f) - 1.0f;
    const float tau = powf(1.0f + c, (float)(i - KPAD));
    s     = 4.0f / tau;
    e     = expf(-s);
    decay = (1.0f - e) / s;
}

// ws slot for (chunk b, taustar i, f4-group lane): float4
__device__ __forceinline__ size_t ws_idx(int b, int i, int lane) {
    return (((size_t)b * NS + i) * 64 + lane) * 4;
}

// init: compute per-taustar constants once (1 block).
__global__ __launch_bounds__(128) void laplace_init(float* __restrict__ tab) {
    const int i = threadIdx.x;
    if (i < NS) {
        float s, e, d;
        laplace_consts(i, s, e, d);
        tab[i]          = e;
        tab[NS + i]     = d;
        tab[2 * NS + i] = expf(-s * (float)CH);   // g = e^CH
    }
}

// Phase A: local 32-step scan from zero state -> L_b
__global__ __launch_bounds__(256) void laplace_local(
    const float* __restrict__ inp,   // (T, F)
    float* __restrict__ ws,          // (NB, NS, 64) float4
    const float* __restrict__ tab)
{
    const int lane = threadIdx.x & 63;
    const int i    = blockIdx.y * 4 + (threadIdx.x >> 6);
    const int b    = blockIdx.x;

    const float e = tab[i];          // wave-uniform scalar load
    const float d = tab[NS + i];

    const float* ip = inp + lane * 4;
    float t0 = 0.f, t1 = 0.f, t2 = 0.f, t3 = 0.f;

    const int n0 = b * CH;
    #pragma unroll 8
    for (int n = n0; n < n0 + CH; ++n) {
        f32x4 x = *(const f32x4*)(ip + (size_t)n * F_DIM);
        t0 = fmaf(e, t0, d * x.x);
        t1 = fmaf(e, t1, d * x.y);
        t2 = fmaf(e, t2, d * x.z);
        t3 = fmaf(e, t3, d * x.w);
    }
    f32x4 r; r.x = t0; r.y = t1; r.z = t2; r.w = t3;
    *(f32x4*)(ws + ws_idx(b, i, lane)) = r;
}

// Phase B: in-place combine -> ws[b] = EXACT state entering chunk b
__global__ __launch_bounds__(256) void laplace_combine(
    float* __restrict__ ws,
    const float* __restrict__ tab)
{
    const int lane = threadIdx.x & 63;
    const int i    = blockIdx.x * 4 + (threadIdx.x >> 6);

    const float g = tab[2 * NS + i];

    float S0 = 0.f, S1 = 0.f, S2 = 0.f, S3 = 0.f;
    #pragma unroll 8
    for (int b = 0; b < NB; ++b) {
        f32x4* p = (f32x4*)(ws + ws_idx(b, i, lane));
        f32x4 L = *p;
        f32x4 S; S.x = S0; S.y = S1; S.z = S2; S.w = S3;
        *p = S;
        S0 = fmaf(g, S0, L.x);
        S1 = fmaf(g, S1, L.y);
        S2 = fmaf(g, S2, L.z);
        S3 = fmaf(g, S3, L.w);
    }
}

// Phase C (R7): LDS-staged, load-free, NONTEMPORAL store burst.
__global__ __launch_bounds__(256) void laplace_burst(
    const float* __restrict__ inp,
    const float* __restrict__ ws,
    const float* __restrict__ tab,
    float* __restrict__ out)         // (T, NS, F)
{
    __shared__ float xs[CH][F_DIM];  // 32 KB

    const int tid  = threadIdx.x;
    const int w    = tid >> 6;          // wave 0..3
    const int lane = tid & 63;
    const int f0   = lane * 4;
    const int ig   = blockIdx.x;        // i-group 0..26
    const int b    = blockIdx.y;        // chunk 0..63
    const int i    = ig * 4 + w;
    const int n0   = b * CH;

    const float e = tab[i];
    const float d = tab[NS + i];

    // --- stage input slice: wave w loads rows w*8 .. w*8+7 (coalesced 1KB/row)
    const float* ip = inp + (size_t)n0 * F_DIM + f0;
    f32x4 v[8];
    #pragma unroll
    for (int r = 0; r < 8; ++r)
        v[r] = *(const f32x4*)(ip + (size_t)(w * 8 + r) * F_DIM);

    // entering state (exact, from phase B)
    f32x4 S = *(const f32x4*)(ws + ws_idx(b, i, lane));

    #pragma unroll
    for (int r = 0; r < 8; ++r)
        *(f32x4*)(&xs[w * 8 + r][f0]) = v[r];
    __syncthreads();

    // --- pure NT store burst: no global loads, no L2 allocation
    float t0 = S.x, t1 = S.y, t2 = S.z, t3 = S.w;
    float* op = out + (size_t)n0 * (NS * F_DIM) + (size_t)i * F_DIM + f0;

    #pragma unroll 8
    for (int n = 0; n < CH; ++n) {
        f32x4 x = *(const f32x4*)(&xs[n][f0]);   // ds_read_b128, lgkmcnt only
        t0 = fmaf(e, t0, d * x.x);
        t1 = fmaf(e, t1, d * x.y);
        t2 = fmaf(e, t2, d * x.z);
        t3 = fmaf(e, t3, d * x.w);
        f32x4 r; r.x = t0; r.y = t1; r.z = t2; r.w = t3;
        __builtin_nontemporal_store(r, (f32x4*)(op + (size_t)n * (NS * F_DIM)));
    }
}

// Fallback (approximate warm-up), used only if ws is too small.
#define CHUNK_FB 64
#define WARM_FB  48
__global__ __launch_bounds__(256) void laplace_kernel_fb(
    const float* __restrict__ inp,
    float* __restrict__ out)
{
    const int tid  = threadIdx.x;
    const int lane = tid & 63;
    const int f0   = lane * 4;
    const int i    = blockIdx.y * 4 + (tid >> 6);
    const int n0   = blockIdx.x * CHUNK_FB;

    float s, e, decay;
    laplace_consts(i, s, e, decay);

    const float* ip = inp + f0;
    float t0 = 0.f, t1 = 0.f, t2 = 0.f, t3 = 0.f;

    int nstart = n0 - WARM_FB;
    if (nstart < 0) nstart = 0;
    #pragma unroll 4
    for (int n = nstart; n < n0; ++n) {
        f32x4 x = *(const f32x4*)(ip + (size_t)n * F_DIM);
        t0 = fmaf(e, t0, decay * x.x);
        t1 = fmaf(e, t1, decay * x.y);
        t2 = fmaf(e, t2, decay * x.z);
        t3 = fmaf(e, t3, decay * x.w);
    }
    float* op = out + (size_t)i * F_DIM + f0;
    #pragma unroll 4
    for (int n = n0; n < n0 + CHUNK_FB; ++n) {
        f32x4 x = *(const f32x4*)(ip + (size_t)n * F_DIM);
        t0 = fmaf(e, t0, decay * x.x);
        t1 = fmaf(e, t1, decay * x.y);
        t2 = fmaf(e, t2, decay * x.z);
        t3 = fmaf(e, t3, decay * x.w);
        f32x4 r; r.x = t0; r.y = t1; r.z = t2; r.w = t3;
        *(f32x4*)(op + (size_t)n * (NS * F_DIM)) = r;
    }
}

extern "C" void kernel_launch(void* const* d_in, const int* in_sizes, int n_in,
                              void* d_out, int out_size, void* d_ws, size_t ws_size,
                              hipStream_t stream) {
    const float* inp = (const float*)d_in[0];
    float* out = (float*)d_out;

    const size_t ws_need = (STATE_FLOATS + 3 * NS) * sizeof(float);  // ~7.08 MB

    if (d_ws != nullptr && ws_size >= ws_need) {
        float* ws  = (float*)d_ws;
        float* tab = ws + STATE_FLOATS;
        laplace_init   <<<dim3(1),          128, 0, stream>>>(tab);
        laplace_local  <<<dim3(NB, NS / 4), 256, 0, stream>>>(inp, ws, tab);
        laplace_combine<<<dim3(NS / 4),     256, 0, stream>>>(ws, tab);
        laplace_burst  <<<dim3(NS / 4, NB), 256, 0, stream>>>(inp, ws, tab, out);
    } else {
        laplace_kernel_fb<<<dim3(T_LEN / CHUNK_FB, NS / 4), 256, 0, stream>>>(inp, out);
    }
}